// Round 12
// baseline (137.842 us; speedup 1.0000x reference)
//
#include <hip/hip_runtime.h>
#include <hip/hip_bf16.h>

// Problem: x(4,256,64,64), offset(4,18,64,64), mask(4,9,64,64),
// weight(256,256,3,3) -> out(4,256,64,64). stride=1, pad=1, K=3.
// R22: split sample/GEMM. R21 post-mortem: 7th round in 115.8-118.6 band;
// fused pinned at ~45us vs ~17-20us pipe floor; every in-structure lever
// (occupancy, pipelining, 3 tile geometries, P/C waves, XCD swizzle,
// head prefetch) <=3us. Split: S writes A[16384][2304]bf16 (72MiB, ws is
// 256MiB per fill evidence) at 32 waves/CU (VALU/write bound, ~17us);
// G is a pure GEMM that can finally use global_load_lds A-staging with
// pre-swizzled source (S stores (lane*8)^((row&7)<<4) within each 512B
// row -> still contiguous; G's ds_read_b128 conflict-free), ~18us.
// Fallback to R21 fused if ws_size < 88MiB.
#define CN 256
#define HN 64
#define WN 64
#define ON 256
#define KKN 9
#define HWN 4096
#define KDIM 2304   // 9*256
#define KC 288      // KDIM/8 chunks

using frag_ab = __attribute__((ext_vector_type(8))) short;  // 8 bf16
using frag_cd = __attribute__((ext_vector_type(4))) float;  // 4 fp32
using short4v = __attribute__((ext_vector_type(4))) short;  // 4 bf16 (8B)
using int4v   = __attribute__((ext_vector_type(4))) int;
using float4v = __attribute__((ext_vector_type(4))) float;
using float2v = __attribute__((ext_vector_type(2))) float;
using uint2v  = __attribute__((ext_vector_type(2))) unsigned;

static __device__ inline short f2bf(float f) {
    union { float f; unsigned u; } v; v.f = f;
    unsigned r = v.u + 0x7fffu + ((v.u >> 16) & 1u);
    return (short)(r >> 16);
}

// ---------- kernel 1: prep = transpose x -> BHWC bf16 | repack weight ----
__global__ __launch_bounds__(256) void prep_kernel(const float* __restrict__ x,
                                                   const float* __restrict__ wsrc,
                                                   short* __restrict__ xb16,
                                                   short* __restrict__ wtb) {
    int bidx = blockIdx.x;
    int tid  = threadIdx.x;
    __shared__ union {
        short tile[128][65];      // 16.6 KB (x-transpose)
        short wlds[16][2312];     // 72.3 KB (weight repack, pad 2312)
    } sm;
    if (bidx < 512) {
        int b  = bidx >> 7;
        int rem = bidx & 127;
        int c0 = (rem >> 6) * 128;
        int p0 = (rem & 63) * 64;
        int pl = tid & 63, wq = tid >> 6;
        #pragma unroll
        for (int i = 0; i < 32; ++i) {
            int cl = wq + i * 4;
            sm.tile[cl][pl] =
                f2bf(x[(size_t)(b * CN + c0 + cl) * HWN + p0 + pl]);
        }
        __syncthreads();
        int c4 = (tid & 31) * 4;
        int pb = tid >> 5;
        #pragma unroll
        for (int s = 0; s < 8; ++s) {
            int p = pb + s * 8;
            short4v v;
            v[0] = sm.tile[c4 + 0][p];
            v[1] = sm.tile[c4 + 1][p];
            v[2] = sm.tile[c4 + 2][p];
            v[3] = sm.tile[c4 + 3][p];
            *(short4v*)&xb16[(size_t)(b * HWN + p0 + p) * CN + c0 + c4] = v;
        }
    } else {
        int o0 = (bidx - 512) * 16;   // 16 o-rows per block
        for (int oi = 0; oi < 16; ++oi) {
            const float* src = &wsrc[(size_t)(o0 + oi) * KDIM + tid * 9];
            short* drow = &sm.wlds[oi][0];
            #pragma unroll
            for (int j = 0; j < 9; ++j)
                drow[j * 256 + tid] = f2bf(src[j]);
        }
        __syncthreads();
        int ob = o0 >> 6, roff = o0 & 63;
        int rl = tid & 15, kc0 = tid >> 4;
        #pragma unroll
        for (int pass = 0; pass < 18; ++pass) {
            int kc  = pass * 16 + kc0;
            int kk  = kc >> 5, oct = kc & 31;
            frag_ab v = *(const frag_ab*)&sm.wlds[rl][kk * 256 + oct * 8];
            *(frag_ab*)&wtb[(size_t)(ob * (KC * 64) + kc * 64 + roff + rl) * 8] = v;
        }
    }
}

// ---------- kernel S: sample -> Ag[t][kk] 32KB tiles, pre-swizzled ----
// grid (256 t-tiles, 9 kk) x 256 thr. Per block: 64 descs (tid<64) then
// 4 waves x 16 rows: gather 4 corner rows (coalesced 512B), combine,
// store 512B/row at (lane*8)^((row&7)<<4) (contiguous, bank-pre-swizzled).
__global__ __launch_bounds__(256) void sample_kernel(const short* __restrict__ xb16,
                                                     const float* __restrict__ offs,
                                                     const float* __restrict__ maskp,
                                                     short* __restrict__ Ag) {
    __shared__ int desc[64 * 8];
    int t   = blockIdx.x;
    int kk  = blockIdx.y;
    int tid = threadIdx.x;
    int b = t >> 6, h = t & 63;
    if (tid < 64) {
        int m = tid;
        int p = h * 64 + m;
        int ki = kk / 3, kj = kk - ki * 3;
        float dy = offs[(b * 18 + 2 * kk) * HWN + p];
        float dx = offs[(b * 18 + 2 * kk + 1) * HWN + p];
        float mv = maskp[(b * 9 + kk) * HWN + p];
        float py = (float)(h - 1 + ki) + dy;
        float px = (float)(m - 1 + kj) + dx;
        float y0f = floorf(py), x0f = floorf(px);
        float wy = py - y0f, wx = px - x0f;
        int y0 = (int)y0f, x0 = (int)x0f;
        int4v cb; float4v cw;
        #pragma unroll
        for (int cy = 0; cy < 2; ++cy)
            #pragma unroll
            for (int cx = 0; cx < 2; ++cx) {
                int yy = y0 + cy, xx = x0 + cx;
                bool valid = (yy >= 0 && yy < HN && xx >= 0 && xx < WN);
                int yc = min(max(yy, 0), HN - 1);
                int xc = min(max(xx, 0), WN - 1);
                cb[cy * 2 + cx] = ((b * HN + yc) * WN + xc) * CN;
                float wgt = (cy ? wy : 1.f - wy) * (cx ? wx : 1.f - wx) * mv;
                cw[cy * 2 + cx] = valid ? wgt : 0.f;
            }
        int* dd = &desc[tid * 8];
        *(int4v*)dd       = cb;
        *(float4v*)(dd + 4) = cw;
    }
    __syncthreads();
    int wv = tid >> 6, lane = tid & 63;
    size_t abase = ((size_t)(t * 9 + kk)) << 15;   // 32KB per (t,kk), bytes
    int soff = lane * 8;                           // lane's 8B slot
    #pragma unroll
    for (int i = 0; i < 16; ++i) {
        int row = wv * 16 + i;
        int4v   cb = *(const int4v*)&desc[row * 8];
        float4v cw = *(const float4v*)&desc[row * 8 + 4];
        short4v stg[4];
        #pragma unroll
        for (int c = 0; c < 4; ++c)                // coalesced 512B rows
            stg[c] = *(const short4v*)&xb16[cb[c] + lane * 4];
        short4v res;
        #pragma unroll
        for (int g = 0; g < 2; ++g) {              // channel pairs
            float2v a = (float2v){0.f, 0.f};
            #pragma unroll
            for (int c = 0; c < 4; ++c) {
                uint2v uv = __builtin_bit_cast(uint2v, stg[c]);
                unsigned uu = uv[g];
                float2v f;
                f.x = __builtin_bit_cast(float, uu << 16);
                f.y = __builtin_bit_cast(float, uu & 0xffff0000u);
                a += f * cw[c];
            }
            __hip_bfloat162 p2 = __float22bfloat162_rn(make_float2(a.x, a.y));
            res[2 * g]     = *(short*)&p2.x;
            res[2 * g + 1] = *(short*)&p2.y;
        }
        int off = (row << 9) + (soff ^ ((row & 7) << 4));
        *(short4v*)((char*)Ag + abase + off) = res;   // contiguous 512B/row
    }
}

// ---------- kernel G: pure GEMM, A via global_load_lds double-buffer ----
// block: 64 rows x 256 cols, 16 waves (wg=wv>>3 row-half, cg=wv&7 col-32).
// Per kk: stage(kk+1) via global_load_lds (16B DMA, no VGPR round-trip),
// consume(kk): ds_read_b128 A (XOR-swizzled, conflict-free) + B ring +
// MFMA; vmcnt(0)+lgkmcnt(0)+barrier per kk (stage had full MFMA phase).
__global__ __launch_bounds__(1024, 1) void gemm_kernel(const short* __restrict__ Ag,
                                                       const short* __restrict__ wtb,
                                                       float* __restrict__ out) {
    __shared__ union {
        short Ab[2][16384];       // 2 x 32 KB dense kk-tiles
        float outb[64 * 257];     // epilogue transpose, pad 257
    } sm;
    int tid  = threadIdx.x;
    int bid  = blockIdx.x;
    int t    = (bid & 7) * 32 + (bid >> 3);   // XCD-contiguous remap
    int b    = t >> 6, h = t & 63;
    int wv   = __builtin_amdgcn_readfirstlane(tid >> 6);   // 0..15
    int lane = tid & 63;
    int q    = lane >> 4, r = lane & 15;
    int wg   = wv >> 3;               // row half 0..1
    int cg   = wv & 7;                // 32-col group 0..7
    int ob   = cg >> 1;               // 64-col block in wtb
    int oh   = (cg & 1) * 32;         // 32-col half within it
    const char* agbase = (const char*)Ag + (((size_t)t * 9) << 15);

    auto stage = [&](int kk, int p) {
        const char* src = agbase + ((size_t)kk << 15);
        char* dst = (char*)&sm.Ab[p][0];
        #pragma unroll
        for (int rd = 0; rd < 2; ++rd) {
            int cb = (wv * 64 + rd * 1024) * 16;
            __builtin_amdgcn_global_load_lds(
                (const unsigned int*)(src + cb + lane * 16),
                (unsigned int*)(dst + cb), 16, 0, 0);
        }
    };

    frag_cd acc[2][2];
    #pragma unroll
    for (int i = 0; i < 2; ++i)
        #pragma unroll
        for (int j = 0; j < 2; ++j)
            acc[i][j] = (frag_cd){0.f, 0.f, 0.f, 0.f};

    auto ld_bf = [&](int kk, int ks, int j) {
        return *(const frag_ab*)
            &wtb[(((size_t)ob * KC + kk * 32 + ks * 4 + q) * 64
                  + oh + j * 16 + r) * 8];
    };
    auto consume = [&](int kk, int p) {
        const char* dstc = (const char*)&sm.Ab[p][0];
        frag_ab bfx[2][2];
        #pragma unroll
        for (int j = 0; j < 2; ++j) {
            bfx[0][j] = ld_bf(kk, 0, j);
            bfx[1][j] = ld_bf(kk, 1, j);
        }
        #pragma unroll
        for (int ks = 0; ks < 8; ++ks) {
            const int cur = ks & 1;
            frag_ab af[2];
            #pragma unroll
            for (int i = 0; i < 2; ++i) {
                int row = wg * 32 + i * 16 + r;
                int off = (row << 9)
                        + ((((ks * 4 + q) << 4)) ^ ((row & 7) << 4));
                af[i] = *(const frag_ab*)(dstc + off);
            }
            __builtin_amdgcn_s_setprio(1);
            #pragma unroll
            for (int i = 0; i < 2; ++i)
                #pragma unroll
                for (int j = 0; j < 2; ++j)
                    acc[i][j] = __builtin_amdgcn_mfma_f32_16x16x32_bf16(
                        af[i], bfx[cur][j], acc[i][j], 0, 0, 0);
            __builtin_amdgcn_s_setprio(0);
            if (ks < 6) {
                #pragma unroll
                for (int j = 0; j < 2; ++j)
                    bfx[cur][j] = ld_bf(kk, ks + 2, j);
            }
        }
    };

    // prologue: stage kk=0, wait, barrier
    stage(0, 0);
    asm volatile("s_waitcnt vmcnt(0)" ::: "memory");
    __builtin_amdgcn_s_barrier();
    asm volatile("" ::: "memory");

    for (int kk = 0; kk < KKN; ++kk) {
        if (kk < 8) stage(kk + 1, (kk + 1) & 1);   // DMA overlaps MFMA
        consume(kk, kk & 1);
        asm volatile("s_waitcnt vmcnt(0) lgkmcnt(0)" ::: "memory");
        __builtin_amdgcn_s_barrier();
        asm volatile("" ::: "memory");
    }

    // epilogue: acc row=wg*32+i*16+q*4+reg, col=cg*32+j*16+r
    #pragma unroll
    for (int i = 0; i < 2; ++i)
        #pragma unroll
        for (int j = 0; j < 2; ++j) {
            int ml = wg * 32 + i * 16 + q * 4;
            int ol = cg * 32 + j * 16 + r;
            sm.outb[(ml + 0) * 257 + ol] = acc[i][j][0];
            sm.outb[(ml + 1) * 257 + ol] = acc[i][j][1];
            sm.outb[(ml + 2) * 257 + ol] = acc[i][j][2];
            sm.outb[(ml + 3) * 257 + ol] = acc[i][j][3];
        }
    __syncthreads();
    {
        int ww = tid & 63;
        int og = tid >> 6;        // 0..15
        #pragma unroll
        for (int oo = 0; oo < 16; ++oo) {
            int o = oo * 16 + og;
            out[(((size_t)b * ON + o) * HN + h) * WN + ww] =
                sm.outb[ww * 257 + o];
        }
    }
}

// ---------- fallback: R21 fused (used only if ws too small) ----------
__global__ __launch_bounds__(1024, 4) void fused_kernel(const short* __restrict__ xb16,
                                                        const short* __restrict__ wtb,
                                                        const float* __restrict__ offs,
                                                        const float* __restrict__ maskp,
                                                        float* __restrict__ out) {
    __shared__ struct {
        union {
            short Ab[2][16640];
            float outb[64 * 257];
        } mix;
        int desc[4608];
    } sm;
    int tid  = threadIdx.x;
    int bid  = blockIdx.x;
    int wgid = (bid & 7) * 32 + (bid >> 3);
    int m0   = wgid * 64;
    int b    = m0 >> 12;
    int h    = (m0 >> 6) & 63;
    int wv   = __builtin_amdgcn_readfirstlane(tid >> 6);
    int lane = tid & 63;
    int q    = lane >> 4, r = lane & 15;
    int wbase = 65 * (lane >> 1) * 8 + (lane & 1) * 4;
    int lane4 = lane * 4;

    if (tid < 576) {
        int kk = tid >> 6;
        int m  = tid & 63;
        int p  = h * 64 + m;
        int ki = kk / 3, kj = kk - ki * 3;
        float dy = offs[(b * 18 + 2 * kk) * HWN + p];
        float dx = offs[(b * 18 + 2 * kk + 1) * HWN + p];
        float mv = maskp[(b * 9 + kk) * HWN + p];
        float py = (float)(h - 1 + ki) + dy;
        float px = (float)(m - 1 + kj) + dx;
        float y0f = floorf(py), x0f = floorf(px);
        float wy = py - y0f, wx = px - x0f;
        int y0 = (int)y0f, x0 = (int)x0f;
        int4v cb; float4v cw;
        #pragma unroll
        for (int cy = 0; cy < 2; ++cy)
            #pragma unroll
            for (int cx = 0; cx < 2; ++cx) {
                int yy = y0 + cy, xx = x0 + cx;
                bool valid = (yy >= 0 && yy < HN && xx >= 0 && xx < WN);
                int yc = min(max(yy, 0), HN - 1);
                int xc = min(max(xx, 0), WN - 1);
                cb[cy * 2 + cx] = ((b * HN + yc) * WN + xc) * CN;
                float wgt = (cy ? wy : 1.f - wy) * (cx ? wx : 1.f - wx) * mv;
                cw[cy * 2 + cx] = valid ? wgt : 0.f;
            }
        int* dd = &sm.desc[tid * 8];
        *(int4v*)dd       = cb;
        *(float4v*)(dd + 4) = cw;
    }
    __syncthreads();

    bool isP = (wv >= 8);
    int  pw8 = (wv - 8) * 8;

    auto g2 = [&](short4v (&stg)[2][4], int tt, int roff) {
        #pragma unroll
        for (int i = 0; i < 2; ++i) {
            int dbase = (tt * 64 + pw8 + roff + i) * 8;
            int4v cb = *(const int4v*)&sm.desc[dbase];
            #pragma unroll
            for (int c = 0; c < 4; ++c)
                stg[i][c] = *(const short4v*)&xb16[cb[c] + lane4];
        }
    };
    auto c2 = [&](short4v (&stg)[2][4], short* dstp, int tt, int roff) {
        #pragma unroll
        for (int i = 0; i < 2; ++i) {
            int mloc = pw8 + roff + i;
            float4v cw = *(const float4v*)&sm.desc[(tt * 64 + mloc) * 8 + 4];
            short4v res;
            #pragma unroll
            for (int g = 0; g < 2; ++g) {
                float2v a = (float2v){0.f, 0.f};
                #pragma unroll
                for (int c = 0; c < 4; ++c) {
                    uint2v uv = __builtin_bit_cast(uint2v, stg[i][c]);
                    unsigned uu = uv[g];
                    float2v f;
                    f.x = __builtin_bit_cast(float, uu << 16);
                    f.y = __builtin_bit_cast(float, uu & 0xffff0000u);
                    a += f * cw[c];
                }
                __hip_bfloat162 p2 = __float22bfloat162_rn(make_float2(a.x, a.y));
                res[2 * g]     = *(short*)&p2.x;
                res[2 * g + 1] = *(short*)&p2.y;
            }
            *(short4v*)&dstp[wbase + mloc * 8] = res;
        }
    };
    auto produce = [&](int tt) {
        short* dstp = sm.mix.Ab[tt & 1];
        short4v sA[2][4], sB[2][4];
        g2(sA, tt, 0);
        g2(sB, tt, 2);
        c2(sA, dstp, tt, 0);
        g2(sA, tt, 4);
        c2(sB, dstp, tt, 2);
        g2(sB, tt, 6);
        c2(sA, dstp, tt, 4);
        c2(sB, dstp, tt, 6);
    };

    frag_cd acc[4][2];
    #pragma unroll
    for (int i = 0; i < 4; ++i)
        #pragma unroll
        for (int j = 0; j < 2; ++j)
            acc[i][j] = (frag_cd){0.f, 0.f, 0.f, 0.f};
    int ob = wv >> 1;
    int oh = (wv & 1) * 32;
    auto ld_bf = [&](int kk, int ks, int j) {
        return *(const frag_ab*)
            &wtb[(((size_t)ob * KC + kk * 32 + ks * 4 + q) * 64
                  + oh + j * 16 + r) * 8];
    };
    frag_ab bfx[2][2];
    auto consume = [&](int kk) {
        const short* dstc = sm.mix.Ab[kk & 1];
        #pragma unroll
        for (int ks = 0; ks < 8; ++ks) {
            const int cur = ks & 1;
            frag_ab af[4];
            #pragma unroll
            for (int i = 0; i < 4; ++i)
                af[i] = *(const frag_ab*)
                    &dstc[(65 * (ks * 4 + q) + i * 16 + r) * 8];
            __builtin_amdgcn_s_setprio(1);
            #pragma unroll
            for (int i = 0; i < 4; ++i)
                #pragma unroll
                for (int j = 0; j < 2; ++j)
                    acc[i][j] = __builtin_amdgcn_mfma_f32_16x16x32_bf16(
                        af[i], bfx[cur][j], acc[i][j], 0, 0, 0);
            __builtin_amdgcn_s_setprio(0);
            if (ks < 6) {
                #pragma unroll
                for (int j = 0; j < 2; ++j)
                    bfx[cur][j] = ld_bf(kk, ks + 2, j);
            }
        }
        if (kk < 8) {
            #pragma unroll
            for (int j = 0; j < 2; ++j) {
                bfx[0][j] = ld_bf(kk + 1, 0, j);
                bfx[1][j] = ld_bf(kk + 1, 1, j);
            }
        }
    };

    if (isP) {
        produce(0);
    } else {
        #pragma unroll
        for (int j = 0; j < 2; ++j) {
            bfx[0][j] = ld_bf(0, 0, j);
            bfx[1][j] = ld_bf(0, 1, j);
        }
    }
    asm volatile("s_waitcnt lgkmcnt(0)" ::: "memory");
    __builtin_amdgcn_s_barrier();
    asm volatile("" ::: "memory");

    for (int kk = 0; kk < KKN; ++kk) {
        if (isP) {
            if (kk < 8) produce(kk + 1);
        } else {
            consume(kk);
        }
        asm volatile("s_waitcnt lgkmcnt(0)" ::: "memory");
        __builtin_amdgcn_s_barrier();
        asm volatile("" ::: "memory");
    }

    if (!isP) {
        #pragma unroll
        for (int i = 0; i < 4; ++i)
            #pragma unroll
            for (int j = 0; j < 2; ++j) {
                int ml = i * 16 + q * 4;
                int ol = wv * 32 + j * 16 + r;
                sm.mix.outb[(ml + 0) * 257 + ol] = acc[i][j][0];
                sm.mix.outb[(ml + 1) * 257 + ol] = acc[i][j][1];
                sm.mix.outb[(ml + 2) * 257 + ol] = acc[i][j][2];
                sm.mix.outb[(ml + 3) * 257 + ol] = acc[i][j][3];
            }
    }
    __syncthreads();
    {
        int ww = tid & 63;
        int og = tid >> 6;
        #pragma unroll
        for (int oo = 0; oo < 16; ++oo) {
            int o = oo * 16 + og;
            out[(((size_t)b * ON + o) * HN + h) * WN + ww] =
                sm.mix.outb[ww * 257 + o];
        }
    }
}

extern "C" void kernel_launch(void* const* d_in, const int* in_sizes, int n_in,
                              void* d_out, int out_size, void* d_ws, size_t ws_size,
                              hipStream_t stream) {
    const float* x      = (const float*)d_in[0];
    const float* offset = (const float*)d_in[1];
    const float* mask   = (const float*)d_in[2];
    const float* weight = (const float*)d_in[3];
    float* out = (float*)d_out;

    // ws: xb16 8 MiB | wtb 1.125 MiB | Ag at 16 MiB, 72 MiB
    short* xb16 = (short*)d_ws;
    short* wtb  = (short*)((char*)d_ws + 8388608);
    short* Ag   = (short*)((char*)d_ws + 16777216);

    hipLaunchKernelGGL(prep_kernel, dim3(528), dim3(256), 0, stream,
                       x, weight, xb16, wtb);
    if (ws_size >= 92274688u) {
        hipLaunchKernelGGL(sample_kernel, dim3(256, 9), dim3(256), 0, stream,
                           xb16, offset, mask, Ag);
        hipLaunchKernelGGL(gemm_kernel, dim3(256), dim3(1024), 0, stream,
                           Ag, wtb, out);
    } else {
        hipLaunchKernelGGL(fused_kernel, dim3(256), dim3(1024), 0, stream,
                           xb16, wtb, offset, mask, out);
    }
}

// Round 13
// 116.108 us; speedup vs baseline: 1.1872x; 1.1872x over previous
//
#include <hip/hip_runtime.h>
#include <hip/hip_bf16.h>

// Problem: x(4,256,64,64), offset(4,18,64,64), mask(4,9,64,64),
// weight(256,256,3,3) -> out(4,256,64,64). stride=1, pad=1, K=3.
// R23 = R17 verbatim (session best, 115.8us measured). R22's split
// sample/GEMM regressed to 137.8 (72MiB A round-trip + extra launch >
// fused's serialization cost) -> fusion wins; revert per decision rule.
// Final decomposition: fill ~46 (harness poison) + ~19 harness
// micro-dispatches + prep ~6 + fused ~44. fused is a structure-local
// minimum: compiler pins VGPR at 64 (R19) so deep pipelines are
// unobtainable; 8 structural levers each measured <=3us. Not a HW
// roofline (all counters <40%) but the reachable plateau for this
// compiler at this problem size.
// Structure: producer/consumer wave specialization. 16 waves: 8 C-waves
// (pure GEMM, 64x32 tile, acc 4x2, 2-ahead B ring) + 8 P-waves (gather+
// combine 8 rows each into A buf[(kk+1)&1]). One lgkmcnt(0)+s_barrier
// per kk; vmcnt never drained in-loop (loads fly across barriers).
#define CN 256
#define HN 64
#define WN 64
#define ON 256
#define KKN 9
#define HWN 4096
#define KDIM 2304   // 9*256
#define KC 288      // KDIM/8 chunks

using frag_ab = __attribute__((ext_vector_type(8))) short;  // 8 bf16
using frag_cd = __attribute__((ext_vector_type(4))) float;  // 4 fp32
using short4v = __attribute__((ext_vector_type(4))) short;  // 4 bf16 (8B)
using int4v   = __attribute__((ext_vector_type(4))) int;
using float4v = __attribute__((ext_vector_type(4))) float;
using float2v = __attribute__((ext_vector_type(2))) float;
using uint2v  = __attribute__((ext_vector_type(2))) unsigned;

static __device__ inline short f2bf(float f) {
    union { float f; unsigned u; } v; v.f = f;
    unsigned r = v.u + 0x7fffu + ((v.u >> 16) & 1u);
    return (short)(r >> 16);
}

// ---------- kernel 1: prep = transpose x -> BHWC bf16 | repack weight ----
__global__ __launch_bounds__(256) void prep_kernel(const float* __restrict__ x,
                                                   const float* __restrict__ wsrc,
                                                   short* __restrict__ xb16,
                                                   short* __restrict__ wtb) {
    int bidx = blockIdx.x;
    int tid  = threadIdx.x;
    if (bidx < 1024) {
        __shared__ float tile[64][65];
        int b   = bidx >> 8;
        int rem = bidx & 255;
        int c0  = (rem >> 6) * 64;
        int p0  = (rem & 63) * 64;
        int tp = tid & 63, tc = tid >> 6;
        for (int i = 0; i < 16; ++i) {
            int c = tc + i * 4;
            tile[c][tp] = x[(b * CN + c0 + c) * HWN + p0 + tp];
        }
        __syncthreads();
        int tcc = tid & 63, tpp = tid >> 6;
        for (int i = 0; i < 16; ++i) {
            int p = tpp + i * 4;
            xb16[(b * HWN + p0 + p) * CN + c0 + tcc] = f2bf(tile[tcc][p]);
        }
    } else {
        int chunk = (bidx - 1024) * 256 + tid;   // < 4*288*64 = 73728
        int ob  = chunk / (KC * 64);
        int rem = chunk - ob * (KC * 64);
        int kc  = rem >> 6;
        int row = rem & 63;
        int o   = ob * 64 + row;
        int kk  = kc >> 5;
        int oct = kc & 31;
        frag_ab v;
        #pragma unroll
        for (int e = 0; e < 8; ++e)
            v[e] = f2bf(wsrc[(o * CN + oct * 8 + e) * 9 + kk]);
        *(frag_ab*)&wtb[(size_t)chunk * 8] = v;
    }
}

// ---------- kernel 2: fused sample + GEMM, producer/consumer ----------
// block: 64 m-rows (one (b,h) row) x 256 o-cols, 16 waves, grid 256.
// C-waves wv 0..7: GEMM tile rows 0..63 x cols wv*32..+32 (acc 4x2).
// P-waves wv 8..15: sample rows (wv-8)*8..+8 into A buf[(kk+1)&1].
// One lgkmcnt(0)+s_barrier per kk; vmcnt never drained in the loop.
__global__ __launch_bounds__(1024, 4) void fused_kernel(const short* __restrict__ xb16,
                                                        const short* __restrict__ wtb,
                                                        const float* __restrict__ offs,
                                                        const float* __restrict__ maskp,
                                                        float* __restrict__ out) {
    __shared__ struct {
        union {
            short Ab[2][16640];       // 2 x 32.5 KB A-tile (stride-65 chunks)
            float outb[64 * 257];     // epilogue transpose, pad 257
        } mix;
        int desc[4608];               // 9 kk x 64 m x 8 dwords = 18 KB
    } sm;
    int tid  = threadIdx.x;
    int m0   = blockIdx.x * 64;
    int b    = m0 >> 12;
    int h    = (m0 >> 6) & 63;        // block = full (b,h) row, w 0..63
    int wv   = __builtin_amdgcn_readfirstlane(tid >> 6);   // 0..15
    int lane = tid & 63;
    int q    = lane >> 4, r = lane & 15;
    // sampling write base (shorts): chunk 65*(lane>>1), half (lane&1)
    int wbase = 65 * (lane >> 1) * 8 + (lane & 1) * 4;
    int lane4 = lane * 4;

    // ---- one-time descriptor compute: thread t<576 -> desc (kk, m) ----
    if (tid < 576) {
        int kk = tid >> 6;
        int m  = tid & 63;            // = w
        int p  = h * 64 + m;
        int ki = kk / 3, kj = kk - ki * 3;
        float dy = offs[(b * 18 + 2 * kk) * HWN + p];
        float dx = offs[(b * 18 + 2 * kk + 1) * HWN + p];
        float mv = maskp[(b * 9 + kk) * HWN + p];
        float py = (float)(h - 1 + ki) + dy;
        float px = (float)(m - 1 + kj) + dx;
        float y0f = floorf(py), x0f = floorf(px);
        float wy = py - y0f, wx = px - x0f;
        int y0 = (int)y0f, x0 = (int)x0f;
        int4v cb; float4v cw;
        #pragma unroll
        for (int cy = 0; cy < 2; ++cy)
            #pragma unroll
            for (int cx = 0; cx < 2; ++cx) {
                int yy = y0 + cy, xx = x0 + cx;
                bool valid = (yy >= 0 && yy < HN && xx >= 0 && xx < WN);
                int yc = min(max(yy, 0), HN - 1);
                int xc = min(max(xx, 0), WN - 1);
                cb[cy * 2 + cx] = ((b * HN + yc) * WN + xc) * CN;
                float wgt = (cy ? wy : 1.f - wy) * (cx ? wx : 1.f - wx) * mv;
                cw[cy * 2 + cx] = valid ? wgt : 0.f;
            }
        int* dd = &sm.desc[tid * 8];
        *(int4v*)dd       = cb;
        *(float4v*)(dd + 4) = cw;
    }
    __syncthreads();

    bool isP = (wv >= 8);
    int  pw8 = (wv - 8) * 8;          // P: first sampled row

    // ---- P-wave helpers: 2-row gather / combine ----
    auto g2 = [&](short4v (&stg)[2][4], int t, int roff) {
        #pragma unroll
        for (int i = 0; i < 2; ++i) {
            int dbase = (t * 64 + pw8 + roff + i) * 8;   // wave-uniform bcast
            int4v cb = *(const int4v*)&sm.desc[dbase];
            #pragma unroll
            for (int c = 0; c < 4; ++c)                  // coalesced 512B rows
                stg[i][c] = *(const short4v*)&xb16[cb[c] + lane4];
        }
    };
    auto c2 = [&](short4v (&stg)[2][4], short* dstp, int t, int roff) {
        #pragma unroll
        for (int i = 0; i < 2; ++i) {
            int mloc = pw8 + roff + i;
            float4v cw = *(const float4v*)&sm.desc[(t * 64 + mloc) * 8 + 4];
            short4v res;
            #pragma unroll
            for (int g = 0; g < 2; ++g) {                // channel pairs
                float2v a = (float2v){0.f, 0.f};
                #pragma unroll
                for (int c = 0; c < 4; ++c) {
                    uint2v uv = __builtin_bit_cast(uint2v, stg[i][c]);
                    unsigned uu = uv[g];
                    float2v f;
                    f.x = __builtin_bit_cast(float, uu << 16);
                    f.y = __builtin_bit_cast(float, uu & 0xffff0000u);
                    a += f * cw[c];
                }
                __hip_bfloat162 p2 = __float22bfloat162_rn(make_float2(a.x, a.y));
                res[2 * g]     = *(short*)&p2.x;
                res[2 * g + 1] = *(short*)&p2.y;
            }
            *(short4v*)&dstp[wbase + mloc * 8] = res;    // ds_write_b64
        }
    };
    auto produce = [&](int t) {
        short* dstp = sm.mix.Ab[t & 1];
        short4v sA[2][4], sB[2][4];
        g2(sA, t, 0);                 // rows 0-1 in flight
        g2(sB, t, 2);                 // rows 2-3 in flight
        c2(sA, dstp, t, 0);
        g2(sA, t, 4);
        c2(sB, dstp, t, 2);
        g2(sB, t, 6);
        c2(sA, dstp, t, 4);
        c2(sB, dstp, t, 6);
    };

    // ---- C-wave state ----
    frag_cd acc[4][2];
    #pragma unroll
    for (int i = 0; i < 4; ++i)
        #pragma unroll
        for (int j = 0; j < 2; ++j)
            acc[i][j] = (frag_cd){0.f, 0.f, 0.f, 0.f};
    int ob = wv >> 1;                 // 64-col block in wtb (C waves: wv 0..7)
    int oh = (wv & 1) * 32;           // 32-col half within it
    auto ld_bf = [&](int kk, int ks, int j) {
        return *(const frag_ab*)
            &wtb[(((size_t)ob * KC + kk * 32 + ks * 4 + q) * 64
                  + oh + j * 16 + r) * 8];
    };
    auto consume = [&](int kk) {
        const short* dstc = sm.mix.Ab[kk & 1];
        frag_ab bfx[2][2];
        #pragma unroll
        for (int j = 0; j < 2; ++j) {
            bfx[0][j] = ld_bf(kk, 0, j);
            bfx[1][j] = ld_bf(kk, 1, j);
        }
        #pragma unroll
        for (int ks = 0; ks < 8; ++ks) {
            const int cur = ks & 1;
            frag_ab af[4];
            #pragma unroll
            for (int i = 0; i < 4; ++i)
                af[i] = *(const frag_ab*)
                    &dstc[(65 * (ks * 4 + q) + i * 16 + r) * 8];
            __builtin_amdgcn_s_setprio(1);
            #pragma unroll
            for (int i = 0; i < 4; ++i)
                #pragma unroll
                for (int j = 0; j < 2; ++j)
                    acc[i][j] = __builtin_amdgcn_mfma_f32_16x16x32_bf16(
                        af[i], bfx[cur][j], acc[i][j], 0, 0, 0);
            __builtin_amdgcn_s_setprio(0);
            if (ks < 6) {
                #pragma unroll
                for (int j = 0; j < 2; ++j)
                    bfx[cur][j] = ld_bf(kk, ks + 2, j);
            }
        }
    };

    // ---- prologue: P builds tile 0; C idles ----
    if (isP) produce(0);
    asm volatile("s_waitcnt lgkmcnt(0)" ::: "memory");
    __builtin_amdgcn_s_barrier();
    asm volatile("" ::: "memory");

    // ---- main loop: C consumes buf[kk&1] while P produces buf[(kk+1)&1].
    for (int kk = 0; kk < KKN; ++kk) {
        if (isP) {
            if (kk < 8) produce(kk + 1);
        } else {
            consume(kk);
        }
        asm volatile("s_waitcnt lgkmcnt(0)" ::: "memory");
        __builtin_amdgcn_s_barrier();
        asm volatile("" ::: "memory");
    }

    // ---- epilogue: C writes acc (row=i*16+q*4+reg, col=wv*32+j*16+r) ----
    if (!isP) {
        #pragma unroll
        for (int i = 0; i < 4; ++i)
            #pragma unroll
            for (int j = 0; j < 2; ++j) {
                int ml = i * 16 + q * 4;
                int ol = wv * 32 + j * 16 + r;
                sm.mix.outb[(ml + 0) * 257 + ol] = acc[i][j][0];
                sm.mix.outb[(ml + 1) * 257 + ol] = acc[i][j][1];
                sm.mix.outb[(ml + 2) * 257 + ol] = acc[i][j][2];
                sm.mix.outb[(ml + 3) * 257 + ol] = acc[i][j][3];
            }
    }
    __syncthreads();
    {
        int ww = tid & 63;        // w within row
        int og = tid >> 6;        // 0..15
        #pragma unroll
        for (int oo = 0; oo < 16; ++oo) {
            int o = oo * 16 + og;
            out[(((size_t)b * ON + o) * HN + h) * WN + ww] =
                sm.mix.outb[ww * 257 + o];
        }
    }
}

extern "C" void kernel_launch(void* const* d_in, const int* in_sizes, int n_in,
                              void* d_out, int out_size, void* d_ws, size_t ws_size,
                              hipStream_t stream) {
    const float* x      = (const float*)d_in[0];
    const float* offset = (const float*)d_in[1];
    const float* mask   = (const float*)d_in[2];
    const float* weight = (const float*)d_in[3];
    float* out = (float*)d_out;

    // ws: xb16 bf16 8 MiB | wtb (B') bf16 1.125 MiB
    short* xb16 = (short*)d_ws;
    short* wtb  = (short*)((char*)d_ws + 8388608);

    hipLaunchKernelGGL(prep_kernel,  dim3(1312), dim3(256),  0, stream,
                       x, weight, xb16, wtb);
    hipLaunchKernelGGL(fused_kernel, dim3(256),  dim3(1024), 0, stream,
                       xb16, wtb, offset, mask, out);
}

// Round 14
// 115.134 us; speedup vs baseline: 1.1972x; 1.0085x over previous
//
#include <hip/hip_runtime.h>
#include <hip/hip_bf16.h>

// Problem: x(4,256,64,64), offset(4,18,64,64), mask(4,9,64,64),
// weight(256,256,3,3) -> out(4,256,64,64). stride=1, pad=1, K=3.
// R24: 2-kk barrier ticks (10 -> 6 barriers).
// R23 confirmed 116.1 (R17 reproduced). fused ~44us over 10 ticks vs
// ~20us of summed pipe work -> ~2.4us/tick lockstep overhead (drain +
// sync + slowest-wave L2 tail). Every in-tick lever measured <=3us;
// tick COUNT never attacked. Now: each buffer = 2-kk A-tile (65KB),
// double-buffered (130KB + 18KB desc = 148.5KB < 160KB, occupancy
// already 1 block/CU). P produces next pair (16 rows), C consumes
// current pair (16 ks), one lgkmcnt(0)+s_barrier per tick. Same
// disjoint-buffer invariant; vmcnt never drained in-loop.
#define CN 256
#define HN 64
#define WN 64
#define ON 256
#define KKN 9
#define HWN 4096
#define KDIM 2304   // 9*256
#define KC 288      // KDIM/8 chunks

using frag_ab = __attribute__((ext_vector_type(8))) short;  // 8 bf16
using frag_cd = __attribute__((ext_vector_type(4))) float;  // 4 fp32
using short4v = __attribute__((ext_vector_type(4))) short;  // 4 bf16 (8B)
using int4v   = __attribute__((ext_vector_type(4))) int;
using float4v = __attribute__((ext_vector_type(4))) float;
using float2v = __attribute__((ext_vector_type(2))) float;
using uint2v  = __attribute__((ext_vector_type(2))) unsigned;

static __device__ inline short f2bf(float f) {
    union { float f; unsigned u; } v; v.f = f;
    unsigned r = v.u + 0x7fffu + ((v.u >> 16) & 1u);
    return (short)(r >> 16);
}

// ---------- kernel 1: prep = transpose x -> BHWC bf16 | repack weight ----
__global__ __launch_bounds__(256) void prep_kernel(const float* __restrict__ x,
                                                   const float* __restrict__ wsrc,
                                                   short* __restrict__ xb16,
                                                   short* __restrict__ wtb) {
    int bidx = blockIdx.x;
    int tid  = threadIdx.x;
    if (bidx < 1024) {
        __shared__ float tile[64][65];
        int b   = bidx >> 8;
        int rem = bidx & 255;
        int c0  = (rem >> 6) * 64;
        int p0  = (rem & 63) * 64;
        int tp = tid & 63, tc = tid >> 6;
        for (int i = 0; i < 16; ++i) {
            int c = tc + i * 4;
            tile[c][tp] = x[(b * CN + c0 + c) * HWN + p0 + tp];
        }
        __syncthreads();
        int tcc = tid & 63, tpp = tid >> 6;
        for (int i = 0; i < 16; ++i) {
            int p = tpp + i * 4;
            xb16[(b * HWN + p0 + p) * CN + c0 + tcc] = f2bf(tile[tcc][p]);
        }
    } else {
        int chunk = (bidx - 1024) * 256 + tid;   // < 4*288*64 = 73728
        int ob  = chunk / (KC * 64);
        int rem = chunk - ob * (KC * 64);
        int kc  = rem >> 6;
        int row = rem & 63;
        int o   = ob * 64 + row;
        int kk  = kc >> 5;
        int oct = kc & 31;
        frag_ab v;
        #pragma unroll
        for (int e = 0; e < 8; ++e)
            v[e] = f2bf(wsrc[(o * CN + oct * 8 + e) * 9 + kk]);
        *(frag_ab*)&wtb[(size_t)chunk * 8] = v;
    }
}

// ---------- kernel 2: fused sample + GEMM, producer/consumer ----------
// block: 64 m-rows (one (b,h) row) x 256 o-cols, 16 waves, grid 256.
// C-waves wv 0..7: GEMM tile rows 0..63 x cols wv*32..+32 (acc 4x2).
// P-waves wv 8..15: sample rows (wv-8)*8..+8.
// Tick t: C consumes kk pair (2t,2t+1) from buf[t&1]; P produces pair
// (2t+2,2t+3) into buf[(t+1)&1]. 5 ticks + prologue = 6 barriers.
__global__ __launch_bounds__(1024, 1) void fused_kernel(const short* __restrict__ xb16,
                                                        const short* __restrict__ wtb,
                                                        const float* __restrict__ offs,
                                                        const float* __restrict__ maskp,
                                                        float* __restrict__ out) {
    __shared__ struct {
        union {
            short Ab[2][2][16640];    // 2 buf x 2 kk-halves x 32.5 KB
            float outb[64 * 257];     // epilogue transpose, pad 257
        } mix;
        int desc[4608];               // 9 kk x 64 m x 8 dwords = 18 KB
    } sm;
    int tid  = threadIdx.x;
    int m0   = blockIdx.x * 64;
    int b    = m0 >> 12;
    int h    = (m0 >> 6) & 63;        // block = full (b,h) row, w 0..63
    int wv   = __builtin_amdgcn_readfirstlane(tid >> 6);   // 0..15
    int lane = tid & 63;
    int q    = lane >> 4, r = lane & 15;
    // sampling write base (shorts): chunk 65*(lane>>1), half (lane&1)
    int wbase = 65 * (lane >> 1) * 8 + (lane & 1) * 4;
    int lane4 = lane * 4;

    // ---- one-time descriptor compute: thread t<576 -> desc (kk, m) ----
    if (tid < 576) {
        int kk = tid >> 6;
        int m  = tid & 63;            // = w
        int p  = h * 64 + m;
        int ki = kk / 3, kj = kk - ki * 3;
        float dy = offs[(b * 18 + 2 * kk) * HWN + p];
        float dx = offs[(b * 18 + 2 * kk + 1) * HWN + p];
        float mv = maskp[(b * 9 + kk) * HWN + p];
        float py = (float)(h - 1 + ki) + dy;
        float px = (float)(m - 1 + kj) + dx;
        float y0f = floorf(py), x0f = floorf(px);
        float wy = py - y0f, wx = px - x0f;
        int y0 = (int)y0f, x0 = (int)x0f;
        int4v cb; float4v cw;
        #pragma unroll
        for (int cy = 0; cy < 2; ++cy)
            #pragma unroll
            for (int cx = 0; cx < 2; ++cx) {
                int yy = y0 + cy, xx = x0 + cx;
                bool valid = (yy >= 0 && yy < HN && xx >= 0 && xx < WN);
                int yc = min(max(yy, 0), HN - 1);
                int xc = min(max(xx, 0), WN - 1);
                cb[cy * 2 + cx] = ((b * HN + yc) * WN + xc) * CN;
                float wgt = (cy ? wy : 1.f - wy) * (cx ? wx : 1.f - wx) * mv;
                cw[cy * 2 + cx] = valid ? wgt : 0.f;
            }
        int* dd = &sm.desc[tid * 8];
        *(int4v*)dd       = cb;
        *(float4v*)(dd + 4) = cw;
    }
    __syncthreads();

    bool isP = (wv >= 8);
    int  pw8 = (wv - 8) * 8;          // P: first sampled row

    // ---- P-wave helpers: 2-row gather / combine (desc index = kk) ----
    auto g2 = [&](short4v (&stg)[2][4], int kk, int roff) {
        #pragma unroll
        for (int i = 0; i < 2; ++i) {
            int dbase = (kk * 64 + pw8 + roff + i) * 8;  // wave-uniform bcast
            int4v cb = *(const int4v*)&sm.desc[dbase];
            #pragma unroll
            for (int c = 0; c < 4; ++c)                  // coalesced 512B rows
                stg[i][c] = *(const short4v*)&xb16[cb[c] + lane4];
        }
    };
    auto c2 = [&](short4v (&stg)[2][4], short* dstp, int kk, int roff) {
        #pragma unroll
        for (int i = 0; i < 2; ++i) {
            int mloc = pw8 + roff + i;
            float4v cw = *(const float4v*)&sm.desc[(kk * 64 + mloc) * 8 + 4];
            short4v res;
            #pragma unroll
            for (int g = 0; g < 2; ++g) {                // channel pairs
                float2v a = (float2v){0.f, 0.f};
                #pragma unroll
                for (int c = 0; c < 4; ++c) {
                    uint2v uv = __builtin_bit_cast(uint2v, stg[i][c]);
                    unsigned uu = uv[g];
                    float2v f;
                    f.x = __builtin_bit_cast(float, uu << 16);
                    f.y = __builtin_bit_cast(float, uu & 0xffff0000u);
                    a += f * cw[c];
                }
                __hip_bfloat162 p2 = __float22bfloat162_rn(make_float2(a.x, a.y));
                res[2 * g]     = *(short*)&p2.x;
                res[2 * g + 1] = *(short*)&p2.y;
            }
            *(short4v*)&dstp[wbase + mloc * 8] = res;    // ds_write_b64
        }
    };
    auto produce = [&](int kk, short* dstp) {
        short4v sA[2][4], sB[2][4];
        g2(sA, kk, 0);                // rows 0-1 in flight
        g2(sB, kk, 2);                // rows 2-3 in flight
        c2(sA, dstp, kk, 0);
        g2(sA, kk, 4);
        c2(sB, dstp, kk, 2);
        g2(sB, kk, 6);
        c2(sA, dstp, kk, 4);
        c2(sB, dstp, kk, 6);
    };

    // ---- C-wave state ----
    frag_cd acc[4][2];
    #pragma unroll
    for (int i = 0; i < 4; ++i)
        #pragma unroll
        for (int j = 0; j < 2; ++j)
            acc[i][j] = (frag_cd){0.f, 0.f, 0.f, 0.f};
    int ob = wv >> 1;                 // 64-col block in wtb (C waves: wv 0..7)
    int oh = (wv & 1) * 32;           // 32-col half within it
    auto ld_bf = [&](int kk, int ks, int j) {
        return *(const frag_ab*)
            &wtb[(((size_t)ob * KC + kk * 32 + ks * 4 + q) * 64
                  + oh + j * 16 + r) * 8];
    };
    auto consume = [&](int kk, const short* dstc) {
        frag_ab bfx[2][2];
        #pragma unroll
        for (int j = 0; j < 2; ++j) {
            bfx[0][j] = ld_bf(kk, 0, j);
            bfx[1][j] = ld_bf(kk, 1, j);
        }
        #pragma unroll
        for (int ks = 0; ks < 8; ++ks) {
            const int cur = ks & 1;
            frag_ab af[4];
            #pragma unroll
            for (int i = 0; i < 4; ++i)
                af[i] = *(const frag_ab*)
                    &dstc[(65 * (ks * 4 + q) + i * 16 + r) * 8];
            __builtin_amdgcn_s_setprio(1);
            #pragma unroll
            for (int i = 0; i < 4; ++i)
                #pragma unroll
                for (int j = 0; j < 2; ++j)
                    acc[i][j] = __builtin_amdgcn_mfma_f32_16x16x32_bf16(
                        af[i], bfx[cur][j], acc[i][j], 0, 0, 0);
            __builtin_amdgcn_s_setprio(0);
            if (ks < 6) {
                #pragma unroll
                for (int j = 0; j < 2; ++j)
                    bfx[cur][j] = ld_bf(kk, ks + 2, j);
            }
        }
    };

    // ---- prologue: P builds pair 0 (kk 0,1) into buf0; C idles ----
    if (isP) {
        produce(0, sm.mix.Ab[0][0]);
        produce(1, sm.mix.Ab[0][1]);
    }
    asm volatile("s_waitcnt lgkmcnt(0)" ::: "memory");
    __builtin_amdgcn_s_barrier();
    asm volatile("" ::: "memory");

    // ---- main loop: tick t: C consumes pair (2t,2t+1) from buf[t&1],
    //      P produces pair (2t+2,2t+3) into buf[(t+1)&1]. ----
    for (int t = 0; t < 5; ++t) {
        if (isP) {
            int k0 = 2 * t + 2;
            if (k0 < KKN)     produce(k0,     sm.mix.Ab[(t + 1) & 1][0]);
            if (k0 + 1 < KKN) produce(k0 + 1, sm.mix.Ab[(t + 1) & 1][1]);
        } else {
            int k0 = 2 * t;
            consume(k0, sm.mix.Ab[t & 1][0]);
            if (k0 + 1 < KKN) consume(k0 + 1, sm.mix.Ab[t & 1][1]);
        }
        asm volatile("s_waitcnt lgkmcnt(0)" ::: "memory");
        __builtin_amdgcn_s_barrier();
        asm volatile("" ::: "memory");
    }

    // ---- epilogue: C writes acc (row=i*16+q*4+reg, col=wv*32+j*16+r) ----
    if (!isP) {
        #pragma unroll
        for (int i = 0; i < 4; ++i)
            #pragma unroll
            for (int j = 0; j < 2; ++j) {
                int ml = i * 16 + q * 4;
                int ol = wv * 32 + j * 16 + r;
                sm.mix.outb[(ml + 0) * 257 + ol] = acc[i][j][0];
                sm.mix.outb[(ml + 1) * 257 + ol] = acc[i][j][1];
                sm.mix.outb[(ml + 2) * 257 + ol] = acc[i][j][2];
                sm.mix.outb[(ml + 3) * 257 + ol] = acc[i][j][3];
            }
    }
    __syncthreads();
    {
        int ww = tid & 63;        // w within row
        int og = tid >> 6;        // 0..15
        #pragma unroll
        for (int oo = 0; oo < 16; ++oo) {
            int o = oo * 16 + og;
            out[(((size_t)b * ON + o) * HN + h) * WN + ww] =
                sm.mix.outb[ww * 257 + o];
        }
    }
}

extern "C" void kernel_launch(void* const* d_in, const int* in_sizes, int n_in,
                              void* d_out, int out_size, void* d_ws, size_t ws_size,
                              hipStream_t stream) {
    const float* x      = (const float*)d_in[0];
    const float* offset = (const float*)d_in[1];
    const float* mask   = (const float*)d_in[2];
    const float* weight = (const float*)d_in[3];
    float* out = (float*)d_out;

    // ws: xb16 bf16 8 MiB | wtb (B') bf16 1.125 MiB
    short* xb16 = (short*)d_ws;
    short* wtb  = (short*)((char*)d_ws + 8388608);

    hipLaunchKernelGGL(prep_kernel,  dim3(1312), dim3(256),  0, stream,
                       x, weight, xb16, wtb);
    hipLaunchKernelGGL(fused_kernel, dim3(256),  dim3(1024), 0, stream,
                       xb16, wtb, offset, mask, out);
}

// Round 15
// 115.133 us; speedup vs baseline: 1.1972x; 1.0000x over previous
//
#include <hip/hip_runtime.h>
#include <hip/hip_bf16.h>

// Problem: x(4,256,64,64), offset(4,18,64,64), mask(4,9,64,64),
// weight(256,256,3,3) -> out(4,256,64,64). stride=1, pad=1, K=3.
// R25 = R24 + inline-asm counted-vmcnt B pipeline in C-waves.
// R24 post-mortem: tick-halving ~1us -> sync wasn't the cost. Tick =
// 17600 cyc vs ~2000 of issue work; gap matches B-ring depth-2 exposing
// ~500-900cyc contended-L2 latency 16x/tick. Compiler refuses deeper
// rings in HIP (VGPR pinned 64, R14/R19/R21). Fix (AITER pattern): B
// loads are asm volatile global_load_dwordx4 (cannot sink; outputs
// live), 4 pairs deep, hand-counted s_waitcnt vmcnt(6,6,6,6,6,4,2,0)
// per ks-pair + sched_barrier(0) (rule #18). Valid because C-waves
// issue NO other VMEM in-loop (desc loads drained by pre-loop
// __syncthreads; vmcnt is per-wave). Ring slot ks&3 reloaded right
// after its MFMAs. Everything else R24 verbatim.
#define CN 256
#define HN 64
#define WN 64
#define ON 256
#define KKN 9
#define HWN 4096
#define KDIM 2304   // 9*256
#define KC 288      // KDIM/8 chunks

using frag_ab = __attribute__((ext_vector_type(8))) short;  // 8 bf16
using frag_cd = __attribute__((ext_vector_type(4))) float;  // 4 fp32
using short4v = __attribute__((ext_vector_type(4))) short;  // 4 bf16 (8B)
using int4v   = __attribute__((ext_vector_type(4))) int;
using float4v = __attribute__((ext_vector_type(4))) float;
using float2v = __attribute__((ext_vector_type(2))) float;
using uint2v  = __attribute__((ext_vector_type(2))) unsigned;

static __device__ inline short f2bf(float f) {
    union { float f; unsigned u; } v; v.f = f;
    unsigned r = v.u + 0x7fffu + ((v.u >> 16) & 1u);
    return (short)(r >> 16);
}

// ---------- kernel 1: prep = transpose x -> BHWC bf16 | repack weight ----
__global__ __launch_bounds__(256) void prep_kernel(const float* __restrict__ x,
                                                   const float* __restrict__ wsrc,
                                                   short* __restrict__ xb16,
                                                   short* __restrict__ wtb) {
    int bidx = blockIdx.x;
    int tid  = threadIdx.x;
    if (bidx < 1024) {
        __shared__ float tile[64][65];
        int b   = bidx >> 8;
        int rem = bidx & 255;
        int c0  = (rem >> 6) * 64;
        int p0  = (rem & 63) * 64;
        int tp = tid & 63, tc = tid >> 6;
        for (int i = 0; i < 16; ++i) {
            int c = tc + i * 4;
            tile[c][tp] = x[(b * CN + c0 + c) * HWN + p0 + tp];
        }
        __syncthreads();
        int tcc = tid & 63, tpp = tid >> 6;
        for (int i = 0; i < 16; ++i) {
            int p = tpp + i * 4;
            xb16[(b * HWN + p0 + p) * CN + c0 + tcc] = f2bf(tile[tcc][p]);
        }
    } else {
        int chunk = (bidx - 1024) * 256 + tid;   // < 4*288*64 = 73728
        int ob  = chunk / (KC * 64);
        int rem = chunk - ob * (KC * 64);
        int kc  = rem >> 6;
        int row = rem & 63;
        int o   = ob * 64 + row;
        int kk  = kc >> 5;
        int oct = kc & 31;
        frag_ab v;
        #pragma unroll
        for (int e = 0; e < 8; ++e)
            v[e] = f2bf(wsrc[(o * CN + oct * 8 + e) * 9 + kk]);
        *(frag_ab*)&wtb[(size_t)chunk * 8] = v;
    }
}

// ---------- kernel 2: fused sample + GEMM, producer/consumer ----------
// block: 64 m-rows (one (b,h) row) x 256 o-cols, 16 waves, grid 256.
// C-waves wv 0..7: GEMM tile rows 0..63 x cols wv*32..+32 (acc 4x2),
//   B via asm 4-pair ring with counted vmcnt. P-waves wv 8..15: sample
//   rows (wv-8)*8..+8. Tick t: C consumes pair (2t,2t+1) from buf[t&1];
//   P produces pair (2t+2,2t+3) into buf[(t+1)&1]. 6 barriers total.
__global__ __launch_bounds__(1024, 1) void fused_kernel(const short* __restrict__ xb16,
                                                        const short* __restrict__ wtb,
                                                        const float* __restrict__ offs,
                                                        const float* __restrict__ maskp,
                                                        float* __restrict__ out) {
    __shared__ struct {
        union {
            short Ab[2][2][16640];    // 2 buf x 2 kk-halves x 32.5 KB
            float outb[64 * 257];     // epilogue transpose, pad 257
        } mix;
        int desc[4608];               // 9 kk x 64 m x 8 dwords = 18 KB
    } sm;
    int tid  = threadIdx.x;
    int m0   = blockIdx.x * 64;
    int b    = m0 >> 12;
    int h    = (m0 >> 6) & 63;        // block = full (b,h) row, w 0..63
    int wv   = __builtin_amdgcn_readfirstlane(tid >> 6);   // 0..15
    int lane = tid & 63;
    int q    = lane >> 4, r = lane & 15;
    // sampling write base (shorts): chunk 65*(lane>>1), half (lane&1)
    int wbase = 65 * (lane >> 1) * 8 + (lane & 1) * 4;
    int lane4 = lane * 4;

    // ---- one-time descriptor compute: thread t<576 -> desc (kk, m) ----
    if (tid < 576) {
        int kk = tid >> 6;
        int m  = tid & 63;            // = w
        int p  = h * 64 + m;
        int ki = kk / 3, kj = kk - ki * 3;
        float dy = offs[(b * 18 + 2 * kk) * HWN + p];
        float dx = offs[(b * 18 + 2 * kk + 1) * HWN + p];
        float mv = maskp[(b * 9 + kk) * HWN + p];
        float py = (float)(h - 1 + ki) + dy;
        float px = (float)(m - 1 + kj) + dx;
        float y0f = floorf(py), x0f = floorf(px);
        float wy = py - y0f, wx = px - x0f;
        int y0 = (int)y0f, x0 = (int)x0f;
        int4v cb; float4v cw;
        #pragma unroll
        for (int cy = 0; cy < 2; ++cy)
            #pragma unroll
            for (int cx = 0; cx < 2; ++cx) {
                int yy = y0 + cy, xx = x0 + cx;
                bool valid = (yy >= 0 && yy < HN && xx >= 0 && xx < WN);
                int yc = min(max(yy, 0), HN - 1);
                int xc = min(max(xx, 0), WN - 1);
                cb[cy * 2 + cx] = ((b * HN + yc) * WN + xc) * CN;
                float wgt = (cy ? wy : 1.f - wy) * (cx ? wx : 1.f - wx) * mv;
                cw[cy * 2 + cx] = valid ? wgt : 0.f;
            }
        int* dd = &sm.desc[tid * 8];
        *(int4v*)dd       = cb;
        *(float4v*)(dd + 4) = cw;
    }
    __syncthreads();   // drains vmcnt(0): C-waves enter the loop clean

    bool isP = (wv >= 8);
    int  pw8 = (wv - 8) * 8;          // P: first sampled row

    // ---- P-wave helpers: 2-row gather / combine (desc index = kk) ----
    auto g2 = [&](short4v (&stg)[2][4], int kk, int roff) {
        #pragma unroll
        for (int i = 0; i < 2; ++i) {
            int dbase = (kk * 64 + pw8 + roff + i) * 8;  // wave-uniform bcast
            int4v cb = *(const int4v*)&sm.desc[dbase];
            #pragma unroll
            for (int c = 0; c < 4; ++c)                  // coalesced 512B rows
                stg[i][c] = *(const short4v*)&xb16[cb[c] + lane4];
        }
    };
    auto c2 = [&](short4v (&stg)[2][4], short* dstp, int kk, int roff) {
        #pragma unroll
        for (int i = 0; i < 2; ++i) {
            int mloc = pw8 + roff + i;
            float4v cw = *(const float4v*)&sm.desc[(kk * 64 + mloc) * 8 + 4];
            short4v res;
            #pragma unroll
            for (int g = 0; g < 2; ++g) {                // channel pairs
                float2v a = (float2v){0.f, 0.f};
                #pragma unroll
                for (int c = 0; c < 4; ++c) {
                    uint2v uv = __builtin_bit_cast(uint2v, stg[i][c]);
                    unsigned uu = uv[g];
                    float2v f;
                    f.x = __builtin_bit_cast(float, uu << 16);
                    f.y = __builtin_bit_cast(float, uu & 0xffff0000u);
                    a += f * cw[c];
                }
                __hip_bfloat162 p2 = __float22bfloat162_rn(make_float2(a.x, a.y));
                res[2 * g]     = *(short*)&p2.x;
                res[2 * g + 1] = *(short*)&p2.y;
            }
            *(short4v*)&dstp[wbase + mloc * 8] = res;    // ds_write_b64
        }
    };
    auto produce = [&](int kk, short* dstp) {
        short4v sA[2][4], sB[2][4];
        g2(sA, kk, 0);                // rows 0-1 in flight
        g2(sB, kk, 2);                // rows 2-3 in flight
        c2(sA, dstp, kk, 0);
        g2(sA, kk, 4);
        c2(sB, dstp, kk, 2);
        g2(sB, kk, 6);
        c2(sA, dstp, kk, 4);
        c2(sB, dstp, kk, 6);
    };

    // ---- C-wave state ----
    frag_cd acc[4][2];
    #pragma unroll
    for (int i = 0; i < 4; ++i)
        #pragma unroll
        for (int j = 0; j < 2; ++j)
            acc[i][j] = (frag_cd){0.f, 0.f, 0.f, 0.f};
    int ob = wv >> 1;                 // 64-col block in wtb (C waves: wv 0..7)
    int oh = (wv & 1) * 32;           // 32-col half within it

// asm B load: saddr form, 32-bit voffset, literal j-offset (0/256 bytes)
#define B_LOAD(dst, voff, OFFLIT)                                          \
    asm volatile("global_load_dwordx4 %0, %1, %2 offset:" OFFLIT           \
                 : "=v"(dst) : "v"(voff), "s"(wtb))

    // consume(kk): 8 ks-steps; B ring 4 pairs deep; counted vmcnt.
    // Per-wave VMEM order: L0..L7 (pairs 0-3) up front, L8..L15 (pairs
    // 4-7) after steps 0-3. Waits 6,6,6,6,6,4,2,0 retire exactly the
    // consumed pair (audited by simulation; C-waves have no other VMEM).
    auto consume = [&](int kk, const short* dstc) {
        unsigned vo0 =
            (((unsigned)(ob * KC + kk * 32 + q)) * 64 + (unsigned)(oh + r)) * 16u;
        frag_ab bfr[8];
        B_LOAD(bfr[0], vo0 + 0u,     "0");
        B_LOAD(bfr[1], vo0 + 0u,     "256");
        B_LOAD(bfr[2], vo0 + 4096u,  "0");
        B_LOAD(bfr[3], vo0 + 4096u,  "256");
        B_LOAD(bfr[4], vo0 + 8192u,  "0");
        B_LOAD(bfr[5], vo0 + 8192u,  "256");
        B_LOAD(bfr[6], vo0 + 12288u, "0");
        B_LOAD(bfr[7], vo0 + 12288u, "256");
#define KSTEP(KS, VMC, ISSUE)                                              \
        do {                                                               \
            frag_ab af[4];                                                 \
            _Pragma("unroll")                                              \
            for (int i = 0; i < 4; ++i)                                    \
                af[i] = *(const frag_ab*)                                  \
                    &dstc[(65 * ((KS) * 4 + q) + i * 16 + r) * 8];         \
            asm volatile("s_waitcnt vmcnt(" #VMC ")");                     \
            __builtin_amdgcn_sched_barrier(0);                             \
            __builtin_amdgcn_s_setprio(1);                                 \
            _Pragma("unroll")                                              \
            for (int i = 0; i < 4; ++i) {                                  \
                acc[i][0] = __builtin_amdgcn_mfma_f32_16x16x32_bf16(       \
                    af[i], bfr[((KS) & 3) * 2 + 0], acc[i][0], 0, 0, 0);   \
                acc[i][1] = __builtin_amdgcn_mfma_f32_16x16x32_bf16(       \
                    af[i], bfr[((KS) & 3) * 2 + 1], acc[i][1], 0, 0, 0);   \
            }                                                              \
            __builtin_amdgcn_s_setprio(0);                                 \
            if (ISSUE) {                                                   \
                B_LOAD(bfr[((KS) & 3) * 2 + 0],                            \
                       vo0 + ((KS) + 4) * 4096u, "0");                     \
                B_LOAD(bfr[((KS) & 3) * 2 + 1],                            \
                       vo0 + ((KS) + 4) * 4096u, "256");                   \
            }                                                              \
        } while (0)
        KSTEP(0, 6, 1);
        KSTEP(1, 6, 1);
        KSTEP(2, 6, 1);
        KSTEP(3, 6, 1);
        KSTEP(4, 6, 0);
        KSTEP(5, 4, 0);
        KSTEP(6, 2, 0);
        KSTEP(7, 0, 0);   // fully drained at consume exit
#undef KSTEP
    };

    // ---- prologue: P builds pair 0 (kk 0,1) into buf0; C idles ----
    if (isP) {
        produce(0, sm.mix.Ab[0][0]);
        produce(1, sm.mix.Ab[0][1]);
    }
    asm volatile("s_waitcnt lgkmcnt(0)" ::: "memory");
    __builtin_amdgcn_s_barrier();
    asm volatile("" ::: "memory");

    // ---- main loop: tick t: C consumes pair (2t,2t+1) from buf[t&1],
    //      P produces pair (2t+2,2t+3) into buf[(t+1)&1]. ----
    for (int t = 0; t < 5; ++t) {
        if (isP) {
            int k0 = 2 * t + 2;
            if (k0 < KKN)     produce(k0,     sm.mix.Ab[(t + 1) & 1][0]);
            if (k0 + 1 < KKN) produce(k0 + 1, sm.mix.Ab[(t + 1) & 1][1]);
        } else {
            int k0 = 2 * t;
            consume(k0, sm.mix.Ab[t & 1][0]);
            if (k0 + 1 < KKN) consume(k0 + 1, sm.mix.Ab[t & 1][1]);
        }
        asm volatile("s_waitcnt lgkmcnt(0)" ::: "memory");
        __builtin_amdgcn_s_barrier();
        asm volatile("" ::: "memory");
    }

    // ---- epilogue: C writes acc (row=i*16+q*4+reg, col=wv*32+j*16+r) ----
    if (!isP) {
        #pragma unroll
        for (int i = 0; i < 4; ++i)
            #pragma unroll
            for (int j = 0; j < 2; ++j) {
                int ml = i * 16 + q * 4;
                int ol = wv * 32 + j * 16 + r;
                sm.mix.outb[(ml + 0) * 257 + ol] = acc[i][j][0];
                sm.mix.outb[(ml + 1) * 257 + ol] = acc[i][j][1];
                sm.mix.outb[(ml + 2) * 257 + ol] = acc[i][j][2];
                sm.mix.outb[(ml + 3) * 257 + ol] = acc[i][j][3];
            }
    }
    __syncthreads();
    {
        int ww = tid & 63;        // w within row
        int og = tid >> 6;        // 0..15
        #pragma unroll
        for (int oo = 0; oo < 16; ++oo) {
            int o = oo * 16 + og;
            out[(((size_t)b * ON + o) * HN + h) * WN + ww] =
                sm.mix.outb[ww * 257 + o];
        }
    }
#undef B_LOAD
}

extern "C" void kernel_launch(void* const* d_in, const int* in_sizes, int n_in,
                              void* d_out, int out_size, void* d_ws, size_t ws_size,
                              hipStream_t stream) {
    const float* x      = (const float*)d_in[0];
    const float* offset = (const float*)d_in[1];
    const float* mask   = (const float*)d_in[2];
    const float* weight = (const float*)d_in[3];
    float* out = (float*)d_out;

    // ws: xb16 bf16 8 MiB | wtb (B') bf16 1.125 MiB
    short* xb16 = (short*)d_ws;
    short* wtb  = (short*)((char*)d_ws + 8388608);

    hipLaunchKernelGGL(prep_kernel,  dim3(1312), dim3(256),  0, stream,
                       x, weight, xb16, wtb);
    hipLaunchKernelGGL(fused_kernel, dim3(256),  dim3(1024), 0, stream,
                       xb16, wtb, offset, mask, out);
}